// Round 20
// baseline (304.366 us; speedup 1.0000x reference)
//
#include <hip/hip_runtime.h>

// Round-20: structural test — remove the K-split and its barrier.
// BM=32, 512 threads (8 waves), grid=256 (1 block/CU, 2 waves/SIMD).
// Phase B: 8 output tiles (4 d-tiles x 2 m-tiles) = 8 waves, each with FULL
// K=512 (w2h[16]) -> no Pb exchange, no 3rd barrier; every wave updates its
// own AB4 state. 2 barriers/step instead of 3. (512,2) -> 256-reg budget.
// Keeps round-19's proven setprio + cvt_pkrtz tweaks and liveness style.

#define NS 8192
#define TT 128
#define DD 64
#define HH 512
#define BM 32
#define NSTEP (TT - 1)

typedef _Float16 half8 __attribute__((ext_vector_type(8)));
typedef _Float16 half4 __attribute__((ext_vector_type(4)));
typedef __fp16 fp16x2 __attribute__((ext_vector_type(2)));
typedef float f32x4 __attribute__((ext_vector_type(4)));

// ws layout (_Float16 elements):
//   W1Th [HH][DD] @ 0        (W1^T, fp16)
//   W2Th [DD][HH] @ 32768    (W2^T, fp16)

__global__ __launch_bounds__(256) void prep_weights(
    const float* __restrict__ W1, const float* __restrict__ W2,
    _Float16* __restrict__ wsp) {
  int idx = blockIdx.x * 256 + threadIdx.x;  // 0..65535
  if (idx < HH * DD) {                       // W1[d][j]
    int d = idx / HH, j = idx % HH;
    wsp[j * DD + d] = (_Float16)W1[idx];
  } else {                                   // W2[j][d]
    int k = idx - HH * DD;
    int j = k / DD, d = k % DD;
    wsp[HH * DD + d * HH + j] = (_Float16)W2[k];
  }
}

__device__ __forceinline__ float fast_tanh(float x) {
  float e = __builtin_amdgcn_exp2f(-2.8853900817779268f * fabsf(x));
  float r = (1.0f - e) * __builtin_amdgcn_rcpf(1.0f + e);
  return copysignf(r, x);
}

__device__ __forceinline__ half4 pack4(float a, float b, float c2, float d) {
  fp16x2 lo = __builtin_amdgcn_cvt_pkrtz(a, b);
  fp16x2 hi = __builtin_amdgcn_cvt_pkrtz(c2, d);
  half4 r;
  r[0] = (_Float16)lo[0]; r[1] = (_Float16)lo[1];
  r[2] = (_Float16)hi[0]; r[3] = (_Float16)hi[1];
  return r;
}

__global__ __launch_bounds__(512, 2) void ode_mfma_kernel(
    const float* __restrict__ ts, const float* __restrict__ hxs,
    const float* __restrict__ masks, const float* __restrict__ b1,
    const float* __restrict__ b2, const _Float16* __restrict__ wsp,
    float* __restrict__ out) {
  // LDS 54.4 KB: Zh 33.3 + Yh 4.6 + DTs 16.5 (1 block/CU).
  __shared__ __align__(16) _Float16 Zh[BM][520];   // 520: floor-banked stride
  __shared__ __align__(16) _Float16 Yh[BM][72];
  __shared__ __align__(16) float DTs[BM][129];

  const int t = threadIdx.x;
  const int w = t >> 6, l = t & 63;   // wave 0..7
  const int c = l & 15, q = l >> 4;
  const int m0 = blockIdx.x * BM;
  // phase-B tile ownership: d-tile db = w>>1 (0..3), m-tile mb = w&1
  const int db = w >> 1, mb = w & 1;
  const int m = mb * 16 + c;          // owned sample row (0..31)
  const int d0 = db * 16 + 4 * q;     // owned dims d0..d0+3

  const _Float16* W1Th = wsp;
  const _Float16* W2Th = wsp + HH * DD;

  // ---- stationary weight fragments ----
  // phase A: wave w owns j-tiles {4w .. 4w+3}
  half8 w1h[4][2];
#pragma unroll
  for (int jl = 0; jl < 4; ++jl)
#pragma unroll
    for (int kk = 0; kk < 2; ++kk) {
      int off = ((4 * w + jl) * 16 + c) * DD + kk * 32 + 8 * q;
      w1h[jl][kk] = *(const half8*)&W1Th[off];
    }
  // phase B: FULL K=512 for d-tile db (16 fragments)
  half8 w2h[16];
#pragma unroll
  for (int kg = 0; kg < 16; ++kg)
    w2h[kg] = *(const half8*)&W2Th[(db * 16 + c) * HH + kg * 32 + 8 * q];

  // biases
  f32x4 b1f[4];
#pragma unroll
  for (int jl = 0; jl < 4; ++jl)
    b1f[jl] = *(const f32x4*)&b1[(4 * w + jl) * 16 + 4 * q];
  const f32x4 b2v = *(const f32x4*)&b2[d0];

  // dt table
  for (int idx = t; idx < BM * TT; idx += 512) {
    int mm = idx >> 7, s = idx & (TT - 1);
    float v = 0.0f;
    if (s < NSTEP) v = ts[(m0 + mm) * TT + s + 1] - ts[(m0 + mm) * TT + s];
    DTs[mm][s] = v;
  }

  // init y-state: every thread owns (m, d0..d0+3) — disjoint, full coverage
  float y[4], f1[4], f2[4], f3[4];
  {
    const float mk = masks[m0 + m];
    f32x4 y0 = *(const f32x4*)&hxs[(m0 + m) * DD + d0];
#pragma unroll
    for (int r = 0; r < 4; ++r) {
      y[r] = y0[r] * mk;
      f1[r] = f2[r] = f3[r] = 0.0f;
    }
    *(half4*)&Yh[m][d0] = pack4(y[0], y[1], y[2], y[3]);
  }
  __syncthreads();

  for (int s = 0; s < NSTEP; ++s) {
    // ---- phase A (swapped): Z^T tiles = W1^T @ Y^T ----
    // wave w: 2 m-tiles x 4 j-tiles; round-10 liveness (one acc at a time)
#pragma unroll
    for (int mbt = 0; mbt < 2; ++mbt) {
      half8 yh[2];
#pragma unroll
      for (int kk = 0; kk < 2; ++kk)
        yh[kk] = *(const half8*)&Yh[mbt * 16 + c][kk * 32 + 8 * q];
#pragma unroll
      for (int jl = 0; jl < 4; ++jl) {
        f32x4 acc = b1f[jl];
        __builtin_amdgcn_s_setprio(1);
#pragma unroll
        for (int kk = 0; kk < 2; ++kk)
          acc = __builtin_amdgcn_mfma_f32_16x16x32_f16(w1h[jl][kk], yh[kk], acc, 0, 0, 0);
        __builtin_amdgcn_s_setprio(0);
        *(half4*)&Zh[mbt * 16 + c][(4 * w + jl) * 16 + 4 * q] =
            pack4(fast_tanh(acc[0]), fast_tanh(acc[1]),
                  fast_tanh(acc[2]), fast_tanh(acc[3]));
      }
    }
    __syncthreads();

    // ---- phase B: F^T tile (db, mb), full K=512, no partial exchange ----
    f32x4 acc = {0.0f, 0.0f, 0.0f, 0.0f};
    __builtin_amdgcn_s_setprio(1);
#pragma unroll
    for (int kg = 0; kg < 16; ++kg) {
      half8 zh = *(const half8*)&Zh[m][kg * 32 + 8 * q];
      acc = __builtin_amdgcn_mfma_f32_16x16x32_f16(w2h[kg], zh, acc, 0, 0, 0);
    }
    __builtin_amdgcn_s_setprio(0);

    // ---- AB4 update: all 8 waves, each its own (m, d0) quadrant ----
    {
      const float dtv = DTs[m][s];
#pragma unroll
      for (int r = 0; r < 4; ++r) {
        float fn = acc[r] + b2v[r];
        float inc;
        if (s == 0)      inc = fn;
        else if (s == 1) inc = (3.0f * fn - f1[r]) * 0.5f;
        else if (s == 2) inc = (23.0f * fn - 16.0f * f1[r] + 5.0f * f2[r]) * (1.0f / 12.0f);
        else             inc = (55.0f * fn - 59.0f * f1[r] + 37.0f * f2[r] - 9.0f * f3[r]) * (1.0f / 24.0f);
        y[r] += dtv * inc;
        f3[r] = f2[r]; f2[r] = f1[r]; f1[r] = fn;
      }
      *(half4*)&Yh[m][d0] = pack4(y[0], y[1], y[2], y[3]);
    }
    __syncthreads();
  }

  // pred = where(ts[:,0]==0, first_point, y_final); every thread writes its quadrant
  {
    const float mk = masks[m0 + m];
    float ts0 = ts[(m0 + m) * TT];
    f32x4 o;
    if (ts0 == 0.0f) {
      f32x4 h4 = *(const f32x4*)&hxs[(m0 + m) * DD + d0];
#pragma unroll
      for (int r = 0; r < 4; ++r) o[r] = h4[r] * mk;
    } else {
#pragma unroll
      for (int r = 0; r < 4; ++r) o[r] = y[r];
    }
    *(f32x4*)&out[(m0 + m) * DD + d0] = o;
  }
}

extern "C" void kernel_launch(void* const* d_in, const int* in_sizes, int n_in,
                              void* d_out, int out_size, void* d_ws, size_t ws_size,
                              hipStream_t stream) {
  const float* ts    = (const float*)d_in[0];
  const float* hxs   = (const float*)d_in[1];
  const float* masks = (const float*)d_in[2];
  const float* W1    = (const float*)d_in[3];
  const float* b1    = (const float*)d_in[4];
  const float* W2    = (const float*)d_in[5];
  const float* b2    = (const float*)d_in[6];
  float* out = (float*)d_out;
  _Float16* wsp = (_Float16*)d_ws;
  (void)in_sizes; (void)n_in; (void)out_size; (void)ws_size;

  prep_weights<<<dim3((2 * HH * DD) / 256), dim3(256), 0, stream>>>(W1, W2, wsp);
  ode_mfma_kernel<<<dim3(NS / BM), dim3(512), 0, stream>>>(ts, hxs, masks, b1, b2, wsp, out);
}

// Round 21
// 264.802 us; speedup vs baseline: 1.1494x; 1.1494x over previous
//
#include <hip/hip_runtime.h>

// Round-21: base = round-19 (287.7 us, best). Round-20 refuted the no-Pb
// 1-domain structure (304 us): two barrier domains beat one fewer barrier.
// This round, VALU-only cuts: (1) tanh(x) = 1 - 2/(1+e^{2x}) — sign-free
// exact form, drops fabs/sub/copysign (3 of 6 full-rate ops per tanh);
// (2) phase-B acc initialized to b2v on ks==0 (free C-operand) — drops
// 4 v_add from the update. Everything else identical to round-19.

#define NS 8192
#define TT 128
#define DD 64
#define HH 512
#define BM 16
#define NSTEP (TT - 1)

typedef _Float16 half8 __attribute__((ext_vector_type(8)));
typedef _Float16 half4 __attribute__((ext_vector_type(4)));
typedef __fp16 fp16x2 __attribute__((ext_vector_type(2)));
typedef float f32x4 __attribute__((ext_vector_type(4)));

// ws layout (_Float16 elements):
//   W1Th [HH][DD] @ 0        (W1^T, fp16)
//   W2Th [DD][HH] @ 32768    (W2^T, fp16)

__global__ __launch_bounds__(256) void prep_weights(
    const float* __restrict__ W1, const float* __restrict__ W2,
    _Float16* __restrict__ wsp) {
  int idx = blockIdx.x * 256 + threadIdx.x;  // 0..65535
  if (idx < HH * DD) {                       // W1[d][j]
    int d = idx / HH, j = idx % HH;
    wsp[j * DD + d] = (_Float16)W1[idx];
  } else {                                   // W2[j][d]
    int k = idx - HH * DD;
    int j = k / DD, d = k % DD;
    wsp[HH * DD + d * HH + j] = (_Float16)W2[k];
  }
}

__device__ __forceinline__ float fast_tanh(float x) {
  // tanh(x) = 1 - 2/(1 + e^{2x}), sign-free: x->+inf -> 1, x->-inf -> -1.
  // e^{2x} = 2^{(2 log2 e) x}. 3 full-rate + 2 trans ops.
  float p = __builtin_amdgcn_exp2f(2.8853900817779268f * x);
  return fmaf(-2.0f, __builtin_amdgcn_rcpf(1.0f + p), 1.0f);
}

__device__ __forceinline__ half4 pack4(float a, float b, float c2, float d) {
  fp16x2 lo = __builtin_amdgcn_cvt_pkrtz(a, b);
  fp16x2 hi = __builtin_amdgcn_cvt_pkrtz(c2, d);
  half4 r;
  r[0] = (_Float16)lo[0]; r[1] = (_Float16)lo[1];
  r[2] = (_Float16)hi[0]; r[3] = (_Float16)hi[1];
  return r;
}

// BM=16, 512 threads (8 waves), grid=512 -> 2 blocks/CU = 16 waves/CU in two
// independent barrier domains. (512,4) -> 128 unified regs/wave (64 arch
// VGPR + AGPRs). Liveness kept at round-10/19 levels (round-18 lesson).
__global__ __launch_bounds__(512, 4) void ode_mfma_kernel(
    const float* __restrict__ ts, const float* __restrict__ hxs,
    const float* __restrict__ masks, const float* __restrict__ b1,
    const float* __restrict__ b2, const _Float16* __restrict__ wsp,
    float* __restrict__ out) {
  // LDS ~31.3 KB/block so two blocks co-reside.
  __shared__ __align__(16) _Float16 Zh[BM][520];   // 16.6 KB (520: floor-banked)
  __shared__ __align__(16) _Float16 Yh[BM][72];    //  2.3 KB
  __shared__ __align__(16) float DTs[BM][129];     //  8.3 KB
  __shared__ __align__(16) float Pb[4][64][4];     //  4.0 KB K-split partials

  const int t = threadIdx.x;
  const int w = t >> 6, l = t & 63;   // wave 0..7
  const int c = l & 15, q = l >> 4;
  const int m0 = blockIdx.x * BM;
  // phase-B roles: d-tile db = w>>1 (0..3), K-half ks = w&1
  const int db = w >> 1, ks = w & 1;
  const int m = c;                    // owned sample (phase B / state)
  const int d0 = db * 16 + 4 * q;     // owned dims d0..d0+3

  const _Float16* W1Th = wsp;
  const _Float16* W2Th = wsp + HH * DD;

  // ---- stationary weight fragments ----
  // phase A: wave w owns col-tiles {4w .. 4w+3}
  half8 w1h[4][2];
#pragma unroll
  for (int jl = 0; jl < 4; ++jl)
#pragma unroll
    for (int kk = 0; kk < 2; ++kk) {
      int off = ((4 * w + jl) * 16 + c) * DD + kk * 32 + 8 * q;
      w1h[jl][kk] = *(const half8*)&W1Th[off];
    }
  // phase B: W2 frags for this wave's K-half (8 of 16 k-steps)
  half8 w2h[8];
#pragma unroll
  for (int kkl = 0; kkl < 8; ++kkl) {
    int kg = ks * 8 + kkl;
    w2h[kkl] = *(const half8*)&W2Th[(db * 16 + c) * HH + kg * 32 + 8 * q];
  }

  // biases
  f32x4 b1f[4];
#pragma unroll
  for (int jl = 0; jl < 4; ++jl)
    b1f[jl] = *(const f32x4*)&b1[(4 * w + jl) * 16 + 4 * q];
  const f32x4 b2v = *(const f32x4*)&b2[d0];

  // dt table
  for (int idx = t; idx < BM * TT; idx += 512) {
    int mm = idx >> 7, s = idx & (TT - 1);
    float v = 0.0f;
    if (s < NSTEP) v = ts[(m0 + mm) * TT + s + 1] - ts[(m0 + mm) * TT + s];
    DTs[mm][s] = v;
  }

  // init y-state: ks==0 waves (db 0..3) cover all (m, d0)
  float y[4], f1[4], f2[4], f3[4];
  if (ks == 0) {
    const float mk = masks[m0 + m];
    f32x4 y0 = *(const f32x4*)&hxs[(m0 + m) * DD + d0];
#pragma unroll
    for (int r = 0; r < 4; ++r) {
      y[r] = y0[r] * mk;
      f1[r] = f2[r] = f3[r] = 0.0f;
    }
    *(half4*)&Yh[m][d0] = pack4(y[0], y[1], y[2], y[3]);
  }
  __syncthreads();

  for (int s = 0; s < NSTEP; ++s) {
    // ---- phase A (swapped): Z^T tiles = W1^T @ Y^T; 4 col-tiles per wave ----
    // Round-10 liveness: one accumulator at a time, tanh+store per jl.
    {
      half8 yh[2];
#pragma unroll
      for (int kk = 0; kk < 2; ++kk)
        yh[kk] = *(const half8*)&Yh[c][kk * 32 + 8 * q];
#pragma unroll
      for (int jl = 0; jl < 4; ++jl) {
        f32x4 acc = b1f[jl];
        __builtin_amdgcn_s_setprio(1);
#pragma unroll
        for (int kk = 0; kk < 2; ++kk)
          acc = __builtin_amdgcn_mfma_f32_16x16x32_f16(w1h[jl][kk], yh[kk], acc, 0, 0, 0);
        __builtin_amdgcn_s_setprio(0);
        *(half4*)&Zh[c][(4 * w + jl) * 16 + 4 * q] =
            pack4(fast_tanh(acc[0]), fast_tanh(acc[1]),
                  fast_tanh(acc[2]), fast_tanh(acc[3]));
      }
    }
    __syncthreads();

    // ---- phase B (swapped, K-split 2): F^T tile db, K-half ks ----
    // acc starts at b2v on the update waves (free C-operand init).
    f32x4 acc;
    if (ks == 0) acc = b2v;
    else         acc = f32x4{0.0f, 0.0f, 0.0f, 0.0f};
    __builtin_amdgcn_s_setprio(1);
#pragma unroll
    for (int kkl = 0; kkl < 8; ++kkl) {
      const int kg = ks * 8 + kkl;
      half8 zh = *(const half8*)&Zh[m][kg * 32 + 8 * q];
      acc = __builtin_amdgcn_mfma_f32_16x16x32_f16(w2h[kkl], zh, acc, 0, 0, 0);
    }
    __builtin_amdgcn_s_setprio(0);
    if (ks == 1) {
      *(f32x4*)&Pb[db][l][0] = acc;
    }
    __syncthreads();

    if (ks == 0) {
      const f32x4 po = *(const f32x4*)&Pb[db][l][0];
      const float dtv = DTs[m][s];
#pragma unroll
      for (int r = 0; r < 4; ++r) {
        float fn = acc[r] + po[r];
        float inc;
        if (s == 0)      inc = fn;
        else if (s == 1) inc = (3.0f * fn - f1[r]) * 0.5f;
        else if (s == 2) inc = (23.0f * fn - 16.0f * f1[r] + 5.0f * f2[r]) * (1.0f / 12.0f);
        else             inc = (55.0f * fn - 59.0f * f1[r] + 37.0f * f2[r] - 9.0f * f3[r]) * (1.0f / 24.0f);
        y[r] += dtv * inc;
        f3[r] = f2[r]; f2[r] = f1[r]; f1[r] = fn;
      }
      *(half4*)&Yh[m][d0] = pack4(y[0], y[1], y[2], y[3]);
    }
    __syncthreads();
  }

  // pred = where(ts[:,0]==0, first_point, y_final); write by ks==0 waves
  if (ks == 0) {
    const float mk = masks[m0 + m];
    float ts0 = ts[(m0 + m) * TT];
    f32x4 o;
    if (ts0 == 0.0f) {
      f32x4 h4 = *(const f32x4*)&hxs[(m0 + m) * DD + d0];
#pragma unroll
      for (int r = 0; r < 4; ++r) o[r] = h4[r] * mk;
    } else {
#pragma unroll
      for (int r = 0; r < 4; ++r) o[r] = y[r];
    }
    *(f32x4*)&out[(m0 + m) * DD + d0] = o;
  }
}

extern "C" void kernel_launch(void* const* d_in, const int* in_sizes, int n_in,
                              void* d_out, int out_size, void* d_ws, size_t ws_size,
                              hipStream_t stream) {
  const float* ts    = (const float*)d_in[0];
  const float* hxs   = (const float*)d_in[1];
  const float* masks = (const float*)d_in[2];
  const float* W1    = (const float*)d_in[3];
  const float* b1    = (const float*)d_in[4];
  const float* W2    = (const float*)d_in[5];
  const float* b2    = (const float*)d_in[6];
  float* out = (float*)d_out;
  _Float16* wsp = (_Float16*)d_ws;
  (void)in_sizes; (void)n_in; (void)out_size; (void)ws_size;

  prep_weights<<<dim3((2 * HH * DD) / 256), dim3(256), 0, stream>>>(W1, W2, wsp);
  ode_mfma_kernel<<<dim3(NS / BM), dim3(512), 0, stream>>>(ts, hxs, masks, b1, b2, wsp, out);
}

// Round 22
// 246.488 us; speedup vs baseline: 1.2348x; 1.0743x over previous
//
#include <hip/hip_runtime.h>

// Round-22: base = round-21 (264.8 us, best). Last micro lever: split the AB4
// update across BOTH ks-groups (ks==0 owns dims d0..d0+1, ks==1 owns
// d0+2..d0+3). Both groups exchange K-half partials via Pb[2] banks; update
// work per thread halves and no wave idles through the update segment.
// Everything else identical to round-21.

#define NS 8192
#define TT 128
#define DD 64
#define HH 512
#define BM 16
#define NSTEP (TT - 1)

typedef _Float16 half8 __attribute__((ext_vector_type(8)));
typedef _Float16 half4 __attribute__((ext_vector_type(4)));
typedef _Float16 half2v __attribute__((ext_vector_type(2)));
typedef __fp16 fp16x2 __attribute__((ext_vector_type(2)));
typedef float f32x4 __attribute__((ext_vector_type(4)));
typedef float f32x2 __attribute__((ext_vector_type(2)));

// ws layout (_Float16 elements):
//   W1Th [HH][DD] @ 0        (W1^T, fp16)
//   W2Th [DD][HH] @ 32768    (W2^T, fp16)

__global__ __launch_bounds__(256) void prep_weights(
    const float* __restrict__ W1, const float* __restrict__ W2,
    _Float16* __restrict__ wsp) {
  int idx = blockIdx.x * 256 + threadIdx.x;  // 0..65535
  if (idx < HH * DD) {                       // W1[d][j]
    int d = idx / HH, j = idx % HH;
    wsp[j * DD + d] = (_Float16)W1[idx];
  } else {                                   // W2[j][d]
    int k = idx - HH * DD;
    int j = k / DD, d = k % DD;
    wsp[HH * DD + d * HH + j] = (_Float16)W2[k];
  }
}

__device__ __forceinline__ float fast_tanh(float x) {
  // tanh(x) = 1 - 2/(1 + e^{2x}), sign-free exact form.
  float p = __builtin_amdgcn_exp2f(2.8853900817779268f * x);
  return fmaf(-2.0f, __builtin_amdgcn_rcpf(1.0f + p), 1.0f);
}

__device__ __forceinline__ half4 pack4(float a, float b, float c2, float d) {
  fp16x2 lo = __builtin_amdgcn_cvt_pkrtz(a, b);
  fp16x2 hi = __builtin_amdgcn_cvt_pkrtz(c2, d);
  half4 r;
  r[0] = (_Float16)lo[0]; r[1] = (_Float16)lo[1];
  r[2] = (_Float16)hi[0]; r[3] = (_Float16)hi[1];
  return r;
}

__device__ __forceinline__ half2v pack2(float a, float b) {
  fp16x2 v = __builtin_amdgcn_cvt_pkrtz(a, b);
  half2v r;
  r[0] = (_Float16)v[0]; r[1] = (_Float16)v[1];
  return r;
}

// BM=16, 512 threads (8 waves), grid=512 -> 2 blocks/CU, two independent
// barrier domains. (512,4) -> 128 unified regs/wave; liveness at round-10/19
// levels (round-18 lesson: never raise peak VALU-visible liveness).
__global__ __launch_bounds__(512, 4) void ode_mfma_kernel(
    const float* __restrict__ ts, const float* __restrict__ hxs,
    const float* __restrict__ masks, const float* __restrict__ b1,
    const float* __restrict__ b2, const _Float16* __restrict__ wsp,
    float* __restrict__ out) {
  // LDS ~35.3 KB/block so two blocks co-reside.
  __shared__ __align__(16) _Float16 Zh[BM][520];   // 16.6 KB (520: floor-banked)
  __shared__ __align__(16) _Float16 Yh[BM][72];    //  2.3 KB
  __shared__ __align__(16) float DTs[BM][129];     //  8.3 KB
  __shared__ __align__(16) float Pb[2][4][64][4];  //  8.0 KB K-half partials

  const int t = threadIdx.x;
  const int w = t >> 6, l = t & 63;   // wave 0..7
  const int c = l & 15, q = l >> 4;
  const int m0 = blockIdx.x * BM;
  // phase-B roles: d-tile db = w>>1 (0..3), K-half ks = w&1
  const int db = w >> 1, ks = w & 1;
  const int m = c;                    // owned sample (phase B / state)
  const int d0 = db * 16 + 4 * q;     // tile dims d0..d0+3
  const int du = d0 + 2 * ks;         // this thread's 2 owned dims: du, du+1

  const _Float16* W1Th = wsp;
  const _Float16* W2Th = wsp + HH * DD;

  // ---- stationary weight fragments ----
  // phase A: wave w owns col-tiles {4w .. 4w+3}
  half8 w1h[4][2];
#pragma unroll
  for (int jl = 0; jl < 4; ++jl)
#pragma unroll
    for (int kk = 0; kk < 2; ++kk) {
      int off = ((4 * w + jl) * 16 + c) * DD + kk * 32 + 8 * q;
      w1h[jl][kk] = *(const half8*)&W1Th[off];
    }
  // phase B: W2 frags for this wave's K-half (8 of 16 k-steps)
  half8 w2h[8];
#pragma unroll
  for (int kkl = 0; kkl < 8; ++kkl) {
    int kg = ks * 8 + kkl;
    w2h[kkl] = *(const half8*)&W2Th[(db * 16 + c) * HH + kg * 32 + 8 * q];
  }

  // biases
  f32x4 b1f[4];
#pragma unroll
  for (int jl = 0; jl < 4; ++jl)
    b1f[jl] = *(const f32x4*)&b1[(4 * w + jl) * 16 + 4 * q];
  const f32x4 b2v = *(const f32x4*)&b2[d0];   // only consumed via ks==0 acc init
  const int ru = 2 * ks;                      // this thread's r-offset (0 or 2)

  // dt table
  for (int idx = t; idx < BM * TT; idx += 512) {
    int mm = idx >> 7, s = idx & (TT - 1);
    float v = 0.0f;
    if (s < NSTEP) v = ts[(m0 + mm) * TT + s + 1] - ts[(m0 + mm) * TT + s];
    DTs[mm][s] = v;
  }

  // init y-state: every thread owns (m, du..du+1) — disjoint, full coverage
  float y[2], f1[2], f2[2], f3[2];
  {
    const float mk = masks[m0 + m];
    f32x2 y0 = *(const f32x2*)&hxs[(m0 + m) * DD + du];
#pragma unroll
    for (int r = 0; r < 2; ++r) {
      y[r] = y0[r] * mk;
      f1[r] = f2[r] = f3[r] = 0.0f;
    }
    *(half2v*)&Yh[m][du] = pack2(y[0], y[1]);
  }
  __syncthreads();

  for (int s = 0; s < NSTEP; ++s) {
    // ---- phase A (swapped): Z^T tiles = W1^T @ Y^T; 4 col-tiles per wave ----
    {
      half8 yh[2];
#pragma unroll
      for (int kk = 0; kk < 2; ++kk)
        yh[kk] = *(const half8*)&Yh[c][kk * 32 + 8 * q];
#pragma unroll
      for (int jl = 0; jl < 4; ++jl) {
        f32x4 acc = b1f[jl];
        __builtin_amdgcn_s_setprio(1);
#pragma unroll
        for (int kk = 0; kk < 2; ++kk)
          acc = __builtin_amdgcn_mfma_f32_16x16x32_f16(w1h[jl][kk], yh[kk], acc, 0, 0, 0);
        __builtin_amdgcn_s_setprio(0);
        *(half4*)&Zh[c][(4 * w + jl) * 16 + 4 * q] =
            pack4(fast_tanh(acc[0]), fast_tanh(acc[1]),
                  fast_tanh(acc[2]), fast_tanh(acc[3]));
      }
    }
    __syncthreads();

    // ---- phase B (swapped, K-split 2): F^T tile db, K-half ks ----
    // b2 is folded into the ks==0 half's C-init (exactly once per fn).
    f32x4 acc;
    if (ks == 0) acc = b2v;
    else         acc = f32x4{0.0f, 0.0f, 0.0f, 0.0f};
    __builtin_amdgcn_s_setprio(1);
#pragma unroll
    for (int kkl = 0; kkl < 8; ++kkl) {
      const int kg = ks * 8 + kkl;
      half8 zh = *(const half8*)&Zh[m][kg * 32 + 8 * q];
      acc = __builtin_amdgcn_mfma_f32_16x16x32_f16(w2h[kkl], zh, acc, 0, 0, 0);
    }
    __builtin_amdgcn_s_setprio(0);
    *(f32x4*)&Pb[ks][db][l][0] = acc;   // both halves publish
    __syncthreads();

    // ---- AB4 update: ALL waves, each thread its 2 owned dims ----
    {
      const f32x4 po = *(const f32x4*)&Pb[ks ^ 1][db][l][0];  // partner half
      const float dtv = DTs[m][s];
#pragma unroll
      for (int r = 0; r < 2; ++r) {
        float fn = acc[r + ru] + po[r + ru];
        float inc;
        if (s == 0)      inc = fn;
        else if (s == 1) inc = (3.0f * fn - f1[r]) * 0.5f;
        else if (s == 2) inc = (23.0f * fn - 16.0f * f1[r] + 5.0f * f2[r]) * (1.0f / 12.0f);
        else             inc = (55.0f * fn - 59.0f * f1[r] + 37.0f * f2[r] - 9.0f * f3[r]) * (1.0f / 24.0f);
        y[r] += dtv * inc;
        f3[r] = f2[r]; f2[r] = f1[r]; f1[r] = fn;
      }
      *(half2v*)&Yh[m][du] = pack2(y[0], y[1]);
    }
    __syncthreads();
  }

  // pred = where(ts[:,0]==0, first_point, y_final); each thread its 2 dims
  {
    const float mk = masks[m0 + m];
    float ts0 = ts[(m0 + m) * TT];
    f32x2 o;
    if (ts0 == 0.0f) {
      f32x2 h2 = *(const f32x2*)&hxs[(m0 + m) * DD + du];
#pragma unroll
      for (int r = 0; r < 2; ++r) o[r] = h2[r] * mk;
    } else {
#pragma unroll
      for (int r = 0; r < 2; ++r) o[r] = y[r];
    }
    *(f32x2*)&out[(m0 + m) * DD + du] = o;
  }
}

extern "C" void kernel_launch(void* const* d_in, const int* in_sizes, int n_in,
                              void* d_out, int out_size, void* d_ws, size_t ws_size,
                              hipStream_t stream) {
  const float* ts    = (const float*)d_in[0];
  const float* hxs   = (const float*)d_in[1];
  const float* masks = (const float*)d_in[2];
  const float* W1    = (const float*)d_in[3];
  const float* b1    = (const float*)d_in[4];
  const float* W2    = (const float*)d_in[5];
  const float* b2    = (const float*)d_in[6];
  float* out = (float*)d_out;
  _Float16* wsp = (_Float16*)d_ws;
  (void)in_sizes; (void)n_in; (void)out_size; (void)ws_size;

  prep_weights<<<dim3((2 * HH * DD) / 256), dim3(256), 0, stream>>>(W1, W2, wsp);
  ode_mfma_kernel<<<dim3(NS / BM), dim3(512), 0, stream>>>(ts, hxs, masks, b1, b2, wsp, out);
}

// Round 23
// 246.266 us; speedup vs baseline: 1.2359x; 1.0009x over previous
//
#include <hip/hip_runtime.h>

// Round-23: base = round-22 (246.5 us, best). Last safe micro: slim the Pb
// partial exchange — each K-half publishes ONLY the 2 dims its partner owns
// (f32x2/b64 instead of f32x4/b128): halves Pb traffic, -2 accvgpr reads
// per thread per step, Pb LDS 8->4 KB. Arithmetic identical to round-22.

#define NS 8192
#define TT 128
#define DD 64
#define HH 512
#define BM 16
#define NSTEP (TT - 1)

typedef _Float16 half8 __attribute__((ext_vector_type(8)));
typedef _Float16 half4 __attribute__((ext_vector_type(4)));
typedef _Float16 half2v __attribute__((ext_vector_type(2)));
typedef __fp16 fp16x2 __attribute__((ext_vector_type(2)));
typedef float f32x4 __attribute__((ext_vector_type(4)));
typedef float f32x2 __attribute__((ext_vector_type(2)));

// ws layout (_Float16 elements):
//   W1Th [HH][DD] @ 0        (W1^T, fp16)
//   W2Th [DD][HH] @ 32768    (W2^T, fp16)

__global__ __launch_bounds__(256) void prep_weights(
    const float* __restrict__ W1, const float* __restrict__ W2,
    _Float16* __restrict__ wsp) {
  int idx = blockIdx.x * 256 + threadIdx.x;  // 0..65535
  if (idx < HH * DD) {                       // W1[d][j]
    int d = idx / HH, j = idx % HH;
    wsp[j * DD + d] = (_Float16)W1[idx];
  } else {                                   // W2[j][d]
    int k = idx - HH * DD;
    int j = k / DD, d = k % DD;
    wsp[HH * DD + d * HH + j] = (_Float16)W2[k];
  }
}

__device__ __forceinline__ float fast_tanh(float x) {
  // tanh(x) = 1 - 2/(1 + e^{2x}), sign-free exact form.
  float p = __builtin_amdgcn_exp2f(2.8853900817779268f * x);
  return fmaf(-2.0f, __builtin_amdgcn_rcpf(1.0f + p), 1.0f);
}

__device__ __forceinline__ half4 pack4(float a, float b, float c2, float d) {
  fp16x2 lo = __builtin_amdgcn_cvt_pkrtz(a, b);
  fp16x2 hi = __builtin_amdgcn_cvt_pkrtz(c2, d);
  half4 r;
  r[0] = (_Float16)lo[0]; r[1] = (_Float16)lo[1];
  r[2] = (_Float16)hi[0]; r[3] = (_Float16)hi[1];
  return r;
}

__device__ __forceinline__ half2v pack2(float a, float b) {
  fp16x2 v = __builtin_amdgcn_cvt_pkrtz(a, b);
  half2v r;
  r[0] = (_Float16)v[0]; r[1] = (_Float16)v[1];
  return r;
}

// BM=16, 512 threads (8 waves), grid=512 -> 2 blocks/CU, two independent
// barrier domains. (512,4) -> 128 unified regs/wave; liveness at round-10/19
// levels (round-18 lesson: never raise peak VALU-visible liveness).
__global__ __launch_bounds__(512, 4) void ode_mfma_kernel(
    const float* __restrict__ ts, const float* __restrict__ hxs,
    const float* __restrict__ masks, const float* __restrict__ b1,
    const float* __restrict__ b2, const _Float16* __restrict__ wsp,
    float* __restrict__ out) {
  // LDS ~31.3 KB/block so two blocks co-reside.
  __shared__ __align__(16) _Float16 Zh[BM][520];   // 16.6 KB (520: floor-banked)
  __shared__ __align__(16) _Float16 Yh[BM][72];    //  2.3 KB
  __shared__ __align__(16) float DTs[BM][129];     //  8.3 KB
  __shared__ __align__(16) float Pb[2][4][64][2];  //  4.0 KB slim K-half partials

  const int t = threadIdx.x;
  const int w = t >> 6, l = t & 63;   // wave 0..7
  const int c = l & 15, q = l >> 4;
  const int m0 = blockIdx.x * BM;
  // phase-B roles: d-tile db = w>>1 (0..3), K-half ks = w&1
  const int db = w >> 1, ks = w & 1;
  const int m = c;                    // owned sample (phase B / state)
  const int d0 = db * 16 + 4 * q;     // tile dims d0..d0+3
  const int du = d0 + 2 * ks;         // this thread's 2 owned dims: du, du+1

  const _Float16* W1Th = wsp;
  const _Float16* W2Th = wsp + HH * DD;

  // ---- stationary weight fragments ----
  // phase A: wave w owns col-tiles {4w .. 4w+3}
  half8 w1h[4][2];
#pragma unroll
  for (int jl = 0; jl < 4; ++jl)
#pragma unroll
    for (int kk = 0; kk < 2; ++kk) {
      int off = ((4 * w + jl) * 16 + c) * DD + kk * 32 + 8 * q;
      w1h[jl][kk] = *(const half8*)&W1Th[off];
    }
  // phase B: W2 frags for this wave's K-half (8 of 16 k-steps)
  half8 w2h[8];
#pragma unroll
  for (int kkl = 0; kkl < 8; ++kkl) {
    int kg = ks * 8 + kkl;
    w2h[kkl] = *(const half8*)&W2Th[(db * 16 + c) * HH + kg * 32 + 8 * q];
  }

  // biases
  f32x4 b1f[4];
#pragma unroll
  for (int jl = 0; jl < 4; ++jl)
    b1f[jl] = *(const f32x4*)&b1[(4 * w + jl) * 16 + 4 * q];
  const f32x4 b2v = *(const f32x4*)&b2[d0];   // consumed via ks==0 acc init
  const int ru = 2 * ks;                      // this thread's r-offset (0 or 2)
  const int pru = 2 - ru;                     // partner's r-offset

  // dt table
  for (int idx = t; idx < BM * TT; idx += 512) {
    int mm = idx >> 7, s = idx & (TT - 1);
    float v = 0.0f;
    if (s < NSTEP) v = ts[(m0 + mm) * TT + s + 1] - ts[(m0 + mm) * TT + s];
    DTs[mm][s] = v;
  }

  // init y-state: every thread owns (m, du..du+1) — disjoint, full coverage
  float y[2], f1[2], f2[2], f3[2];
  {
    const float mk = masks[m0 + m];
    f32x2 y0 = *(const f32x2*)&hxs[(m0 + m) * DD + du];
#pragma unroll
    for (int r = 0; r < 2; ++r) {
      y[r] = y0[r] * mk;
      f1[r] = f2[r] = f3[r] = 0.0f;
    }
    *(half2v*)&Yh[m][du] = pack2(y[0], y[1]);
  }
  __syncthreads();

  for (int s = 0; s < NSTEP; ++s) {
    // ---- phase A (swapped): Z^T tiles = W1^T @ Y^T; 4 col-tiles per wave ----
    {
      half8 yh[2];
#pragma unroll
      for (int kk = 0; kk < 2; ++kk)
        yh[kk] = *(const half8*)&Yh[c][kk * 32 + 8 * q];
#pragma unroll
      for (int jl = 0; jl < 4; ++jl) {
        f32x4 acc = b1f[jl];
        __builtin_amdgcn_s_setprio(1);
#pragma unroll
        for (int kk = 0; kk < 2; ++kk)
          acc = __builtin_amdgcn_mfma_f32_16x16x32_f16(w1h[jl][kk], yh[kk], acc, 0, 0, 0);
        __builtin_amdgcn_s_setprio(0);
        *(half4*)&Zh[c][(4 * w + jl) * 16 + 4 * q] =
            pack4(fast_tanh(acc[0]), fast_tanh(acc[1]),
                  fast_tanh(acc[2]), fast_tanh(acc[3]));
      }
    }
    __syncthreads();

    // ---- phase B (swapped, K-split 2): F^T tile db, K-half ks ----
    // b2 folded into the ks==0 half's C-init (exactly once per fn).
    f32x4 acc;
    if (ks == 0) acc = b2v;
    else         acc = f32x4{0.0f, 0.0f, 0.0f, 0.0f};
    __builtin_amdgcn_s_setprio(1);
#pragma unroll
    for (int kkl = 0; kkl < 8; ++kkl) {
      const int kg = ks * 8 + kkl;
      half8 zh = *(const half8*)&Zh[m][kg * 32 + 8 * q];
      acc = __builtin_amdgcn_mfma_f32_16x16x32_f16(w2h[kkl], zh, acc, 0, 0, 0);
    }
    __builtin_amdgcn_s_setprio(0);
    {
      f32x2 pub;                       // publish ONLY the partner's 2 dims
      pub[0] = acc[pru]; pub[1] = acc[pru + 1];
      *(f32x2*)&Pb[ks][db][l][0] = pub;
    }
    __syncthreads();

    // ---- AB4 update: ALL waves, each thread its 2 owned dims ----
    {
      const f32x2 po = *(const f32x2*)&Pb[ks ^ 1][db][l][0];  // partner half
      const float dtv = DTs[m][s];
#pragma unroll
      for (int r = 0; r < 2; ++r) {
        float fn = acc[r + ru] + po[r];
        float inc;
        if (s == 0)      inc = fn;
        else if (s == 1) inc = (3.0f * fn - f1[r]) * 0.5f;
        else if (s == 2) inc = (23.0f * fn - 16.0f * f1[r] + 5.0f * f2[r]) * (1.0f / 12.0f);
        else             inc = (55.0f * fn - 59.0f * f1[r] + 37.0f * f2[r] - 9.0f * f3[r]) * (1.0f / 24.0f);
        y[r] += dtv * inc;
        f3[r] = f2[r]; f2[r] = f1[r]; f1[r] = fn;
      }
      *(half2v*)&Yh[m][du] = pack2(y[0], y[1]);
    }
    __syncthreads();
  }

  // pred = where(ts[:,0]==0, first_point, y_final); each thread its 2 dims
  {
    const float mk = masks[m0 + m];
    float ts0 = ts[(m0 + m) * TT];
    f32x2 o;
    if (ts0 == 0.0f) {
      f32x2 h2 = *(const f32x2*)&hxs[(m0 + m) * DD + du];
#pragma unroll
      for (int r = 0; r < 2; ++r) o[r] = h2[r] * mk;
    } else {
#pragma unroll
      for (int r = 0; r < 2; ++r) o[r] = y[r];
    }
    *(f32x2*)&out[(m0 + m) * DD + du] = o;
  }
}

extern "C" void kernel_launch(void* const* d_in, const int* in_sizes, int n_in,
                              void* d_out, int out_size, void* d_ws, size_t ws_size,
                              hipStream_t stream) {
  const float* ts    = (const float*)d_in[0];
  const float* hxs   = (const float*)d_in[1];
  const float* masks = (const float*)d_in[2];
  const float* W1    = (const float*)d_in[3];
  const float* b1    = (const float*)d_in[4];
  const float* W2    = (const float*)d_in[5];
  const float* b2    = (const float*)d_in[6];
  float* out = (float*)d_out;
  _Float16* wsp = (_Float16*)d_ws;
  (void)in_sizes; (void)n_in; (void)out_size; (void)ws_size;

  prep_weights<<<dim3((2 * HH * DD) / 256), dim3(256), 0, stream>>>(W1, W2, wsp);
  ode_mfma_kernel<<<dim3(NS / BM), dim3(512), 0, stream>>>(ts, hxs, masks, b1, b2, wsp, out);
}